// Round 10
// baseline (111.522 us; speedup 1.0000x reference)
//
#include <hip/hip_runtime.h>
#include <hip/hip_bf16.h>
#include <cstdint>
#include <cstddef>

#define Nn 8
#define Cc 128
#define Oo 128
#define Hh 64
#define Ww 64
#define LL (Hh * Ww)
#define KP 9

#define XROW 8448              // 66*128 shorts per padded row
#define XTP_N 557568           // 66*66*128 shorts per image
#define WT2_SHORTS (3 * KP * 4 * 4096)   // 442368
#define SLAB 20480             // bytes per pipeline slab (A 8192 + B 12288)

typedef __attribute__((ext_vector_type(8))) short short8;
typedef __attribute__((ext_vector_type(4))) float floatx4;
typedef __attribute__((ext_vector_type(4))) int intx4;

__device__ __forceinline__ unsigned short f2bf(float f) {
  unsigned int u = __float_as_uint(f);
  u += 0x7fffu + ((u >> 16) & 1u);   // round-to-nearest-even
  return (unsigned short)(u >> 16);
}

__device__ __forceinline__ void gl_lds16(const void* g, void* l) {
  __builtin_amdgcn_global_load_lds(
      (const __attribute__((address_space(1))) unsigned int*)g,
      (__attribute__((address_space(3))) unsigned int*)l, 16, 0, 0);
}

// Weak barrier: wait for all but the newest 5 VMEM ops (= this step's 5 DMA
// stages), then s_barrier. In-order vmcnt retirement guarantees the previous
// step's slab writes have landed for every wave before any wave proceeds.
// This is the AITER "vmcnt never 0" pattern __syncthreads can't express.
#define WAVE_BARRIER() asm volatile("s_waitcnt vmcnt(5)\n\ts_barrier" ::: "memory")

// Fused prep:
//  [0,512):    x[n][c][h][w] fp32 -> xtp[n][1+h][1+w][c] bf16 (zero-padded halo)
//  [512,896):  w_b[o][c][3][3] fp32 -> wt2 fragment-contiguous bf16
//  [896,1024): depth -> packed 27-bit branch-mask codes per pixel
//  [1024,1040): zero xtp borders (ws is 0xAA-poisoned before every call)
__global__ __launch_bounds__(256) void prep_all(const float* __restrict__ x,
                                                const float* __restrict__ w0,
                                                const float* __restrict__ w1,
                                                const float* __restrict__ w2,
                                                const float* __restrict__ depth,
                                                const float* __restrict__ fx,
                                                unsigned short* __restrict__ xtp,
                                                unsigned short* __restrict__ wt2,
                                                unsigned int* __restrict__ codesg) {
  __shared__ float tile[Cc][Ww + 1];
  __shared__ unsigned short wl[Cc * KP];
  const int bid = blockIdx.x;
  const int t = threadIdx.x;
  if (bid < Nn * Hh) {
    const int n = bid >> 6;
    const int h = bid & 63;
    const float* src = x + (size_t)n * Cc * LL + (size_t)h * Ww;
#pragma unroll
    for (int it = 0; it < 8; ++it) {
      const int idx = t + it * 256;          // 0..2047
      const int c = idx >> 4;
      const int w4 = (idx & 15) << 2;
      const float4 v = *reinterpret_cast<const float4*>(src + (size_t)c * LL + w4);
      tile[c][w4 + 0] = v.x; tile[c][w4 + 1] = v.y;
      tile[c][w4 + 2] = v.z; tile[c][w4 + 3] = v.w;
    }
    __syncthreads();
    unsigned short* dst = xtp + (size_t)n * XTP_N + (size_t)(h + 1) * XROW + 128;
#pragma unroll
    for (int it = 0; it < 4; ++it) {
      const int idx = t + it * 256;          // 0..1023
      const int w = idx >> 4;
      const int ch = (idx & 15) << 3;
      short8 v;
#pragma unroll
      for (int q = 0; q < 8; ++q)
        ((unsigned short*)&v)[q] = f2bf(tile[ch + q][w]);
      *reinterpret_cast<short8*>(dst + (size_t)w * Cc + ch) = v;
    }
  } else if (bid < Nn * Hh + 3 * Oo) {
    const int bo = bid - Nn * Hh;            // 0..383
    const int b = bo >> 7;
    const int o = bo & 127;
    const float* w = (b == 0) ? w0 : (b == 1) ? w1 : w2;
    const float* src = w + (size_t)o * Cc * KP;   // contiguous 1152 floats
#pragma unroll
    for (int it = 0; it < 5; ++it) {
      const int idx = t + it * 256;
      if (idx < Cc * KP) wl[idx] = f2bf(src[idx]);   // wl[c*9+kk]
    }
    __syncthreads();
    const int obase = ((o >> 6) & 1) * 2048 + ((o >> 5) & 1) * 1024 +
                      ((o >> 4) & 1) * 512 + (o & 15) * 32;
#pragma unroll
    for (int it = 0; it < 5; ++it) {
      const int idx = t + it * 256;          // 0..1151 = kk*128 + c
      if (idx < Cc * KP) {
        const int kk = idx >> 7;
        const int c = idx & 127;
        wt2[(size_t)(b * 36 + kk * 4 + (c >> 5)) * 4096 + obase + (c & 31)] = wl[c * KP + kk];
      }
    }
  } else if (bid < Nn * Hh + 3 * Oo + 128) {
    const int p = (bid - (Nn * Hh + 3 * Oo)) * 256 + t;   // 0..32767
    const int n = p >> 12;
    const int rem = p & 4095;
    const int h = rem >> 6;
    const int w = rem & 63;
    const float center = depth[p];
    const float grid = center / fx[n];       // PIXEL_SIZE*DILATION = 1
    const float half = 0.5f * grid;
    unsigned int packed = 0u;
#pragma unroll
    for (int kk = 0; kk < KP; ++kk) {
      const int hh = h + kk / 3 - 1;
      const int ww = w + kk % 3 - 1;
      float d = 0.0f;
      if (hh >= 0 && hh < Hh && ww >= 0 && ww < Ww) d = depth[(n << 12) + hh * Ww + ww];
      const float valid = (d != 0.0f && center != 0.0f) ? 1.0f : 0.0f;
      const float dm = d * valid;
      unsigned int cb = 0u;
      if (fabsf(dm - (center + grid)) <= half) cb |= 1u;
      float m1v = (fabsf(dm - center) <= half) ? 1.0f : 0.0f;
      m1v = m1v + 1.0f - valid;
      if (m1v > 1.0f) m1v = 1.0f;
      if (m1v > 0.5f) cb |= 2u;
      if (fabsf(dm - (center - grid)) <= half) cb |= 4u;
      packed |= cb << (3 * kk);
    }
    codesg[p] = packed;
  } else {
    // zero xtp borders
    const int b = bid - (Nn * Hh + 3 * Oo + 128);   // 0..15
    const int n = b >> 1;
    unsigned short* base = xtp + (size_t)n * XTP_N;
    const short8 z = {0, 0, 0, 0, 0, 0, 0, 0};
    if ((b & 1) == 0) {
#pragma unroll
      for (int it = 0; it < 9; ++it) {
        const int idx = t + it * 256;
        if (idx < 2112) {
          const int r = (idx < 1056) ? 0 : 65;
          const int off = (idx % 1056) * 8;
          *reinterpret_cast<short8*>(base + (size_t)r * XROW + off) = z;
        }
      }
    } else {
#pragma unroll
      for (int it = 0; it < 8; ++it) {
        const int idx = t + it * 256;      // 0..2047
        const int c = (idx < 1024) ? 0 : 65;
        const int k = idx & 1023;
        const int row = 1 + (k >> 4);
        const int ch = (k & 15) * 8;
        *reinterpret_cast<short8*>(base + (size_t)row * XROW + (size_t)c * 128 + ch) = z;
      }
    }
  }
}

// Triple-buffered DMA pipeline GEMM with WEAK barriers:
//  per step s: issue DMA for step s+2 (5 global_load_lds / wave), consume slab
//  s%3, then `s_waitcnt vmcnt(5); s_barrier` — the DMA queue never drains, so
//  L2 latency is pipelined across steps instead of re-paid 36 times.
__global__ __launch_bounds__(256, 2) void conv_main(
    const unsigned short* __restrict__ xtp,
    const unsigned short* __restrict__ wt2,
    const unsigned int* __restrict__ codesg,
    float* __restrict__ out) {
  __shared__ __align__(16) char slabs[3 * SLAB];   // 61440 B

  const int g = blockIdx.x;          // 512 blocks
  const int n = g >> 6;
  const int rem = g & 63;
  const int pb = rem >> 1;           // 0..31  -> row pair
  const int ob1 = rem & 1;           // o-half
  const int h0 = pb * 2;

  const int tid = threadIdx.x;
  const int lane = tid & 63;
  const int wv = tid >> 6;
  const int ln15 = lane & 15;
  const int quad = lane >> 4;
  const int mh = wv >> 1;            // m-half (0/1)
  const int wc = wv & 1;             // o 32-slice

  // ---- hoisted per-lane staging gather bases ----
  const unsigned short* gA[2];
#pragma unroll
  for (int t = 0; t < 2; ++t) {
    const int a = wv * 2 + t;
    const int pix = a * 16 + (lane >> 2);
    const int col = lane & 3;
    const int q = (col - pix - (pix >> 2)) & 3;          // inverse xor-col swizzle
    gA[t] = xtp + (size_t)n * XTP_N
            + (size_t)((h0 + (pix >> 6)) * 66 + (pix & 63)) * 128 + q * 8;
  }
  const unsigned short* gB[3];
  int ldsB[3];
#pragma unroll
  for (int t = 0; t < 3; ++t) {
    const int bI = wv * 3 + t;
    const int bb = bI >> 2, q4 = bI & 3;
    const int o = q4 * 16 + (lane >> 2);
    const int col = lane & 3;
    const int q = (col - o - (o >> 2)) & 3;
    gB[t] = wt2 + (size_t)bb * (KP * 4 * 4096) + ob1 * 2048 + o * 32 + q * 8;
    ldsB[t] = 8192 + bb * 4096 + q4 * 1024;
  }

  // ---- hoisted per-lane fragment-read offsets (within a slab) ----
  int aRd[4];
#pragma unroll
  for (int i = 0; i < 4; ++i) {
    const int p = mh * 64 + i * 16 + ln15;
    const int col = (quad + p + (p >> 2)) & 3;
    aRd[i] = p * 64 + col * 16;
  }
  int bRd[3][2];
#pragma unroll
  for (int bb = 0; bb < 3; ++bb)
#pragma unroll
    for (int j = 0; j < 2; ++j) {
      const int o = wc * 32 + j * 16 + ln15;
      const int col = (quad + o + (o >> 2)) & 3;
      bRd[bb][j] = 8192 + bb * 4096 + o * 64 + col * 16;
    }

  // stage step sigma into slab at byte offset stgOff (5 DMA issues per wave)
  auto stage = [&](int sigma, int stgOff) {
    const int kk2 = sigma >> 2;
    const int c02 = sigma & 3;
    const int dyp = (kk2 * 11) >> 5;                 // kk2 / 3
    const int dxp = kk2 - 3 * dyp;
    const int aoff = ((dyp * 66 + dxp) * 128 + c02 * 32) * 2;
#pragma unroll
    for (int t = 0; t < 2; ++t)
      gl_lds16((const char*)gA[t] + aoff, slabs + stgOff + (wv * 2 + t) * 1024);
    const int boff = sigma * 8192;
#pragma unroll
    for (int t = 0; t < 3; ++t)
      gl_lds16((const char*)gB[t] + boff, slabs + stgOff + ldsB[t]);
  };

  // ---- branch-mask codes (loaded first: oldest vmcnt entries, retire early) ----
  unsigned int cd[4];
  {
    const unsigned int* cp = codesg + (n << 12) + h0 * 64 + mh * 64 + ln15;
#pragma unroll
    for (int i = 0; i < 4; ++i) cd[i] = cp[i * 16];
  }

  const floatx4 zf4 = {0.f, 0.f, 0.f, 0.f};
  floatx4 acc[4][2];
#pragma unroll
  for (int i = 0; i < 4; ++i) {
    acc[i][0] = zf4; acc[i][1] = zf4;
  }

  // ---- prologue: stage steps 0,1; weak drain (leaves stage(1) in flight) ----
  stage(0, 0);
  stage(1, SLAB);
  WAVE_BARRIER();

  // step s = 3*tt + U consumes slab U, stages slab (U+2)%3 — all compile-time.
#define STEP(U)                                                                 \
  {                                                                             \
    const int sigma = s0 + (U);                                                 \
    if (sigma + 2 < 36) stage(sigma + 2, (((U) + 2) % 3) * SLAB);               \
    const char* slabC = slabs + (U) * SLAB;                                     \
    short8 Af[4], Bf[3][2];                                                     \
    _Pragma("unroll")                                                           \
    for (int i = 0; i < 4; ++i)                                                 \
      Af[i] = *reinterpret_cast<const short8*>(slabC + aRd[i]);                 \
    _Pragma("unroll")                                                           \
    for (int bb = 0; bb < 3; ++bb) {                                            \
      Bf[bb][0] = *reinterpret_cast<const short8*>(slabC + bRd[bb][0]);         \
      Bf[bb][1] = *reinterpret_cast<const short8*>(slabC + bRd[bb][1]);         \
    }                                                                           \
    const int sh3 = 3 * (sigma >> 2);                                           \
    _Pragma("unroll")                                                           \
    for (int bb = 0; bb < 3; ++bb) {                                            \
      _Pragma("unroll")                                                         \
      for (int i = 0; i < 4; ++i) {                                             \
        const int msk = __builtin_amdgcn_sbfe((int)cd[i], sh3 + bb, 1);         \
        intx4 a4 = *reinterpret_cast<const intx4*>(&Af[i]);                     \
        const intx4 m4 = {msk, msk, msk, msk};                                  \
        a4 &= m4;                                                               \
        const short8 af = *reinterpret_cast<const short8*>(&a4);                \
        acc[i][0] = __builtin_amdgcn_mfma_f32_16x16x32_bf16(af, Bf[bb][0], acc[i][0], 0, 0, 0); \
        acc[i][1] = __builtin_amdgcn_mfma_f32_16x16x32_bf16(af, Bf[bb][1], acc[i][1], 0, 0, 0); \
      }                                                                         \
    }                                                                           \
    WAVE_BARRIER();                                                             \
  }

#pragma unroll 1
  for (int tt = 0; tt < 12; ++tt) {
    const int s0 = 3 * tt;
    STEP(0) STEP(1) STEP(2)
  }
#undef STEP

  // ---- epilogue: D row = m (quad*4+reg), col = o (lane&15) ----
#pragma unroll
  for (int i = 0; i < 4; ++i) {
    const int m = mh * 64 + i * 16 + quad * 4;
    const int h = h0 + (m >> 6);
    const int w = m & 63;
#pragma unroll
    for (int j = 0; j < 2; ++j) {
      const int o = ob1 * 64 + wc * 32 + j * 16 + ln15;
      float* dst = out + (size_t)(n * Oo + o) * LL + h * Ww + w;
      *reinterpret_cast<floatx4*>(dst) = acc[i][j];
    }
  }
}

extern "C" void kernel_launch(void* const* d_in, const int* in_sizes, int n_in,
                              void* d_out, int out_size, void* d_ws, size_t ws_size,
                              hipStream_t stream) {
  const float* x     = (const float*)d_in[0];
  const float* depth = (const float*)d_in[1];
  const float* fx    = (const float*)d_in[2];
  const float* w0    = (const float*)d_in[3];
  const float* w1    = (const float*)d_in[4];
  const float* w2    = (const float*)d_in[5];
  float* out = (float*)d_out;

  // ws layout: xtp (8.92 MB padded) | wt2 (864 KB) | codes (128 KB)
  unsigned short* xtp = (unsigned short*)d_ws;
  unsigned short* wt2 = xtp + (size_t)Nn * XTP_N;
  unsigned int* codesg = (unsigned int*)(wt2 + (size_t)WT2_SHORTS);

  prep_all<<<Nn * Hh + 3 * Oo + 128 + 16, 256, 0, stream>>>(x, w0, w1, w2, depth, fx,
                                                            xtp, wt2, codesg);
  conv_main<<<512, 256, 0, stream>>>(xtp, wt2, codesg, out);
}